// Round 20
// baseline (226.021 us; speedup 1.0000x reference)
//
#include <hip/hip_runtime.h>
#include <hip/hip_bf16.h>
#include <stdint.h>

typedef __attribute__((ext_vector_type(8))) short short8;
typedef __attribute__((ext_vector_type(4))) short short4_t;
typedef __attribute__((ext_vector_type(4))) float f32x4;
typedef unsigned short u16;
typedef unsigned int u32;

#define C_ 512

__device__ __forceinline__ u16 f2b(float f){
  u32 u = __float_as_uint(f);
  u += 0x7FFFu + ((u >> 16) & 1u);
  return (u16)(u >> 16);
}
__device__ __forceinline__ float b2f(u16 h){ return __uint_as_float(((u32)h) << 16); }

__device__ __forceinline__ u16 f2b_n(float f){
  __hip_bfloat16 b = __float2bfloat16(f);
  return *reinterpret_cast<u16*>(&b);
}

__device__ __forceinline__ short8 cvt8v(f32x4 lo, f32x4 hi){
  short8 r;
  r[0]=(short)f2b_n(lo[0]); r[1]=(short)f2b_n(lo[1]); r[2]=(short)f2b_n(lo[2]); r[3]=(short)f2b_n(lo[3]);
  r[4]=(short)f2b_n(hi[0]); r[5]=(short)f2b_n(hi[1]); r[6]=(short)f2b_n(hi[2]); r[7]=(short)f2b_n(hi[3]);
  return r;
}

// ---------------- prep: k2/v2 = agent @ W + b ----------------
__global__ __launch_bounds__(256) void prep_kv(
    const float* __restrict__ agent_k, const float* __restrict__ Wk, const float* __restrict__ bk,
    const float* __restrict__ agent_v, const float* __restrict__ Wv, const float* __restrict__ bv,
    float* __restrict__ k2, float* __restrict__ v2)
{
  const int kv = blockIdx.x >> 6;
  const int c0 = (blockIdx.x & 63) * 8;
  const int t = threadIdx.x;
  const float* ag = kv ? agent_v : agent_k;
  const float* W  = kv ? Wv : Wk;
  const float* bb = kv ? bv : bk;
  float* dst      = kv ? v2 : k2;

  __shared__ float ash[16*512];
  __shared__ float part[32][16][8];

  for (int i = t; i < 8192; i += 256) ash[i] = ag[i];
  __syncthreads();
  const int cl = t & 7, ks = t >> 3;
  float s[16];
  #pragma unroll
  for (int a = 0; a < 16; ++a) s[a] = 0.f;
  #pragma unroll
  for (int i = 0; i < 16; ++i) {
    const int cc = ks*16 + i;
    const float wv = W[(size_t)cc*C_ + c0 + cl];
    #pragma unroll
    for (int a = 0; a < 16; ++a) s[a] += ash[a*512 + cc] * wv;
  }
  #pragma unroll
  for (int a = 0; a < 16; ++a) part[ks][a][cl] = s[a];
  __syncthreads();
  if (t < 128) {
    const int a = t >> 3, c = t & 7;
    float v = bb[c0 + c];
    #pragma unroll
    for (int k = 0; k < 32; ++k) v += part[k][a][c];
    dst[a*C_ + c0 + c] = v;
  }
}

// merged: blocks 0..511 -> WqkTr, blocks 512..639 -> WvpTr (r19-validated)
__global__ __launch_bounds__(256) void prep_w(
    const float* __restrict__ Wq, const float* __restrict__ bq, const float* __restrict__ k2,
    const float* __restrict__ Wp, const float* __restrict__ v2,
    u16* __restrict__ WqkTr, float* __restrict__ bqk, u16* __restrict__ WvpTr)
{
  const int bx = blockIdx.x;
  const int t = threadIdx.x;
  if (bx < 512) {
    const int ha = t >> 1, half = t & 1;
    const int c = bx, h = ha >> 4, a = ha & 15;
    const f32x4* wq4 = (const f32x4*)(Wq + (size_t)c*C_ + h*64) + half*8;
    const f32x4* k24 = (const f32x4*)(k2 + (size_t)a*C_ + h*64) + half*8;
    float s = 0.f;
    #pragma unroll
    for (int d4 = 0; d4 < 8; ++d4) {
      f32x4 wv = wq4[d4], kv = k24[d4];
      s += wv[0]*kv[0] + wv[1]*kv[1] + wv[2]*kv[2] + wv[3]*kv[3];
    }
    s += __shfl_xor(s, 1);
    if (half == 0) {
      const int kt = c >> 5, rg = (c >> 3) & 3, e = c & 7;
      const int ct = ha >> 4, la = ha & 15;
      WqkTr[(((kt*8 + ct)*64) + rg*16 + la)*8 + e] = f2b(s * 0.125f);
    }
    if (c == 0) {
      const f32x4* bq4 = (const f32x4*)(bq + h*64) + half*8;
      float sb = 0.f;
      #pragma unroll
      for (int d4 = 0; d4 < 8; ++d4) {
        f32x4 wv = bq4[d4], kv = k24[d4];
        sb += wv[0]*kv[0] + wv[1]*kv[1] + wv[2]*kv[2] + wv[3]*kv[3];
      }
      sb += __shfl_xor(sb, 1);
      if (half == 0) bqk[ha] = sb * 0.125f;
    }
  } else {
    __shared__ float vsh[64];
    const int ha = bx - 512, h = ha >> 4, a = ha & 15;
    if (t < 64) vsh[t] = v2[a*C_ + h*64 + t];
    __syncthreads();
    const int kt = ha >> 5, rg = (ha >> 3) & 3, e = ha & 7;
    const int half = t & 1;
    #pragma unroll
    for (int it = 0; it < 4; ++it) {
      const int co = it*128 + (t >> 1);
      float s = 0.f;
      #pragma unroll
      for (int d = 0; d < 32; ++d) {
        const int dd = half*32 + d;
        s += vsh[dd] * Wp[(size_t)(h*64 + dd)*C_ + co];
      }
      s += __shfl_xor(s, 1);
      if (half == 0) {
        const int cb = co >> 7, ct = (co >> 4) & 7, la = co & 15;
        WvpTr[((((cb*4 + kt)*8 + ct)*64) + rg*16 + la)*8 + e] = f2b(s);
      }
    }
  }
}

// ---------------- pass A: 64-row tiles, 16KB LDS (8 phases x 2 kt), 8 blocks/CU ----------------
__global__ __launch_bounds__(256, 8) void pass_a(
    const float* __restrict__ x, const u16* __restrict__ WqkTr,
    const float* __restrict__ bqk, u16* __restrict__ attn,
    float* __restrict__ gpart)
{
  __shared__ __align__(16) u16 Bs[8192];    // 16 KB exact; ps/pm aliased post-K-loop

  const int t = threadIdx.x;
  const int m0 = blockIdx.x * 64;
  const int w = t >> 6, lane = t & 63;
  const int la = lane & 15, rg = lane >> 4;

  const float* xr = x + (size_t)(m0 + w*16 + la)*C_ + rg*8;

  f32x4 acc[8];
  #pragma unroll
  for (int j = 0; j < 8; ++j) acc[j] = (f32x4){0.f,0.f,0.f,0.f};

  f32x4 pr[2][2];                           // depth-2 kt ring
#define LOADKT(slot, kt) \
  pr[slot][0] = *(const f32x4*)(xr + (kt)*32);     \
  pr[slot][1] = *(const f32x4*)(xr + (kt)*32 + 4);

  LOADKT(0, 0); LOADKT(1, 1);

  #pragma unroll
  for (int ph = 0; ph < 8; ++ph) {
    __syncthreads();
    {
      const short8* gs = (const short8*)WqkTr + ph*1024 + t;
      short8* ld = (short8*)Bs + t;
      #pragma unroll
      for (int i = 0; i < 4; ++i) ld[i*256] = gs[i*256];
    }
    __syncthreads();
    #pragma unroll
    for (int k2i = 0; k2i < 2; ++k2i) {
      const int kt = ph*2 + k2i;
      const int sl = kt & 1;
      short8 b0 = cvt8v(pr[sl][0], pr[sl][1]);
      if (kt < 14) { LOADKT(sl, kt + 2); }
      const u16* fb = Bs + (size_t)k2i*4096 + lane*8;
      #pragma unroll
      for (int ct = 0; ct < 8; ++ct) {
        short8 af = *(const short8*)(fb + ct*512);
        acc[ct] = __builtin_amdgcn_mfma_f32_16x16x32_bf16(af, b0, acc[ct], 0, 0, 0);
      }
    }
  }
#undef LOADKT

  // epilogue: softmax over a (in-register) + attn write + gating partials
  float psj[4] = {0.f,0.f,0.f,0.f};
  float pmj[4] = {0.f,0.f,0.f,0.f};
  const int row = m0 + w*16 + la;

  #pragma unroll
  for (int ct = 0; ct < 8; ++ct) {
    const f32x4 bb = *(const f32x4*)(bqk + ct*16 + rg*4);
    float e0 = __expf(acc[ct][0] + bb[0]);
    float e1 = __expf(acc[ct][1] + bb[1]);
    float e2 = __expf(acc[ct][2] + bb[2]);
    float e3 = __expf(acc[ct][3] + bb[3]);
    float s = e0 + e1 + e2 + e3;
    s += __shfl_xor(s, 16); s += __shfl_xor(s, 32);
    float r = __builtin_amdgcn_rcpf(s);
    float p0 = e0*r, p1 = e1*r, p2 = e2*r, p3 = e3*r;
    psj[0] += p0; psj[1] += p1; psj[2] += p2; psj[3] += p3;
    pmj[0] = fmaxf(pmj[0], p0); pmj[1] = fmaxf(pmj[1], p1);
    pmj[2] = fmaxf(pmj[2], p2); pmj[3] = fmaxf(pmj[3], p3);
    short4_t st;
    st[0]=(short)f2b(p0); st[1]=(short)f2b(p1); st[2]=(short)f2b(p2); st[3]=(short)f2b(p3);
    *(short4_t*)(attn + (size_t)row*128 + ct*16 + rg*4) = st;
  }

  __syncthreads();                          // all Bs reads done -> alias ps/pm
  float* psm = (float*)Bs;
  #pragma unroll
  for (int j = 0; j < 4; ++j) {
    float s = psj[j], m = pmj[j];
    s += __shfl_xor(s, 1); s += __shfl_xor(s, 2); s += __shfl_xor(s, 4); s += __shfl_xor(s, 8);
    m = fmaxf(m, __shfl_xor(m, 1)); m = fmaxf(m, __shfl_xor(m, 2));
    m = fmaxf(m, __shfl_xor(m, 4)); m = fmaxf(m, __shfl_xor(m, 8));
    if (la == 0) { psm[w*16 + rg*4 + j] = s; psm[64 + w*16 + rg*4 + j] = m; }
  }
  __syncthreads();
  if (t < 16) {
    float s = psm[t] + psm[16 + t] + psm[32 + t] + psm[48 + t];
    float m = fmaxf(fmaxf(psm[64 + t], psm[80 + t]), fmaxf(psm[96 + t], psm[112 + t]));
    gpart[(size_t)blockIdx.x*32 + t]      = s;
    gpart[(size_t)blockIdx.x*32 + 16 + t] = m;
  }
}

// ---------------- pass B: 64-row tiles, 16KB LDS (2 halves per cb), 8 blocks/CU ----------------
__global__ __launch_bounds__(256, 8) void pass_b(
    const u16* __restrict__ attn, const u16* __restrict__ WvpTr,
    const float* __restrict__ gpart, const float* __restrict__ ca_w1,
    const float* __restrict__ ca_w2, const float* __restrict__ bp,
    float* __restrict__ out)
{
  __shared__ __align__(16) u16 Bs[8192];    // 16 KB; gsh aliased pre-staging
  const int bx = blockIdx.x;
  const int mb = (bx & 7)*256 + (bx >> 3);  // XCD swizzle over 2048
  const int b = mb >> 6;
  const int t = threadIdx.x;
  const int w = t >> 6, lane = t & 63;
  const int la = lane & 15, rg = lane >> 4;
  const int row = mb*64 + w*16 + la;

  // attn fragments once
  const u16* br = attn + (size_t)row*128 + rg*8;
  short8 bf[4];
  #pragma unroll
  for (int kt = 0; kt < 4; ++kt) bf[kt] = *(const short8*)(br + kt*32);

  // gate MLP from per-block partials (t<16), gsh aliased onto Bs
  float* ga = (float*)Bs;
  if (t < 16) {
    float s = 0.f, m = 0.f;
    #pragma unroll 4
    for (int blk = 0; blk < 64; ++blk) {
      const float* gp = gpart + (size_t)(b*64 + blk)*32;
      s += gp[t]; m = fmaxf(m, gp[16 + t]);
    }
    float c1 = s * (1.0f/32768.0f) * ca_w1[t];
    float c2 = m * ca_w1[t];
    c1 += __shfl_xor(c1, 1); c1 += __shfl_xor(c1, 2); c1 += __shfl_xor(c1, 4); c1 += __shfl_xor(c1, 8);
    c2 += __shfl_xor(c2, 1); c2 += __shfl_xor(c2, 2); c2 += __shfl_xor(c2, 4); c2 += __shfl_xor(c2, 8);
    float g1 = fmaxf(c1, 0.f) + fmaxf(c2, 0.f);
    ga[t] = 1.f / (1.f + __expf(-g1 * ca_w2[t]));
  }
  __syncthreads();

  // gate folded into P-fragments once: k&15 = (rg&1)*8 + e
  float ge[8];
  #pragma unroll
  for (int e = 0; e < 8; ++e) ge[e] = ga[(rg & 1)*8 + e];
  #pragma unroll
  for (int kt = 0; kt < 4; ++kt) {
    short8 v0 = bf[kt];
    #pragma unroll
    for (int e = 0; e < 8; ++e) v0[e] = (short)f2b(b2f((u16)v0[e]) * ge[e]);
    bf[kt] = v0;
  }

  #pragma unroll 1
  for (int cb = 0; cb < 4; ++cb) {
    f32x4 acc[8];
    #pragma unroll
    for (int j = 0; j < 8; ++j) acc[j] = (f32x4){0.f,0.f,0.f,0.f};

    #pragma unroll 1
    for (int half = 0; half < 2; ++half) {
      __syncthreads();                      // ga consumed / prior reads done
      {
        const short8* gs = (const short8*)WvpTr + cb*2048 + half*1024 + t;
        short8* ld = (short8*)Bs + t;
        #pragma unroll
        for (int i = 0; i < 4; ++i) ld[i*256] = gs[i*256];
      }
      __syncthreads();

      #pragma unroll
      for (int k2i = 0; k2i < 2; ++k2i) {
        const u16* fb = Bs + (size_t)k2i*4096 + lane*8;
        const short8 bfr = bf[half*2 + k2i];
        #pragma unroll
        for (int ct = 0; ct < 8; ++ct) {
          short8 af = *(const short8*)(fb + ct*512);
          acc[ct] = __builtin_amdgcn_mfma_f32_16x16x32_bf16(af, bfr, acc[ct], 0, 0, 0);
        }
      }
    }

    #pragma unroll
    for (int ct = 0; ct < 8; ++ct) {
      const int col = cb*128 + ct*16 + rg*4;
      const f32x4 bb = *(const f32x4*)(bp + col);
      f32x4 o;
      o[0] = acc[ct][0] + bb[0];
      o[1] = acc[ct][1] + bb[1];
      o[2] = acc[ct][2] + bb[2];
      o[3] = acc[ct][3] + bb[3];
      *(f32x4*)(out + (size_t)row*C_ + col) = o;
    }
  }
}

// ---------------- launch ----------------
extern "C" void kernel_launch(void* const* d_in, const int* in_sizes, int n_in,
                              void* d_out, int out_size, void* d_ws, size_t ws_size,
                              hipStream_t stream)
{
  const float* x       = (const float*)d_in[0];
  const float* Wq      = (const float*)d_in[1];
  const float* bq      = (const float*)d_in[2];
  const float* Wk      = (const float*)d_in[3];
  const float* bk      = (const float*)d_in[4];
  const float* Wv      = (const float*)d_in[5];
  const float* bv      = (const float*)d_in[6];
  const float* Wp      = (const float*)d_in[7];
  const float* bp      = (const float*)d_in[8];
  const float* agent_k = (const float*)d_in[9];
  const float* agent_v = (const float*)d_in[10];
  const float* ca_w1   = (const float*)d_in[11];
  const float* ca_w2   = (const float*)d_in[12];
  float* out = (float*)d_out;

  char* ws = (char*)d_ws;
  u16*   attn   = (u16*)(ws);                          // 33,554,432 B
  float* k2     = (float*)(ws + 33554432);             // 32768
  float* v2     = (float*)(ws + 33587200);             // 32768
  u16*   WqkTr  = (u16*)(ws + 33619968);               // 131072
  float* bqk    = (float*)(ws + 33751040);             // 2048
  u16*   WvpTr  = (u16*)(ws + 33753088);               // 131072
  float* gpart  = (float*)(ws + 33884160);             // 2048*32*4 = 262144

  prep_kv<<<128, 256, 0, stream>>>(agent_k, Wk, bk, agent_v, Wv, bv, k2, v2);
  prep_w<<<640, 256, 0, stream>>>(Wq, bq, k2, Wp, v2, WqkTr, bqk, WvpTr);
  pass_a<<<2048, 256, 0, stream>>>(x, WqkTr, bqk, attn, gpart);
  pass_b<<<2048, 256, 0, stream>>>(attn, WvpTr, gpart, ca_w1, ca_w2, bp, out);
}

// Round 21
// 197.951 us; speedup vs baseline: 1.1418x; 1.1418x over previous
//
#include <hip/hip_runtime.h>
#include <hip/hip_bf16.h>
#include <stdint.h>

typedef __attribute__((ext_vector_type(8))) short short8;
typedef __attribute__((ext_vector_type(4))) short short4_t;
typedef __attribute__((ext_vector_type(4))) float f32x4;
typedef unsigned short u16;
typedef unsigned int u32;

#define C_ 512

__device__ __forceinline__ u16 f2b(float f){
  u32 u = __float_as_uint(f);
  u += 0x7FFFu + ((u >> 16) & 1u);
  return (u16)(u >> 16);
}
__device__ __forceinline__ float b2f(u16 h){ return __uint_as_float(((u32)h) << 16); }

__device__ __forceinline__ u16 f2b_n(float f){
  __hip_bfloat16 b = __float2bfloat16(f);
  return *reinterpret_cast<u16*>(&b);
}

__device__ __forceinline__ short8 cvt8v(f32x4 lo, f32x4 hi){
  short8 r;
  r[0]=(short)f2b_n(lo[0]); r[1]=(short)f2b_n(lo[1]); r[2]=(short)f2b_n(lo[2]); r[3]=(short)f2b_n(lo[3]);
  r[4]=(short)f2b_n(hi[0]); r[5]=(short)f2b_n(hi[1]); r[6]=(short)f2b_n(hi[2]); r[7]=(short)f2b_n(hi[3]);
  return r;
}

// ---------------- prep: k2/v2 = agent @ W + b ----------------
__global__ __launch_bounds__(256) void prep_kv(
    const float* __restrict__ agent_k, const float* __restrict__ Wk, const float* __restrict__ bk,
    const float* __restrict__ agent_v, const float* __restrict__ Wv, const float* __restrict__ bv,
    float* __restrict__ k2, float* __restrict__ v2)
{
  const int kv = blockIdx.x >> 6;
  const int c0 = (blockIdx.x & 63) * 8;
  const int t = threadIdx.x;
  const float* ag = kv ? agent_v : agent_k;
  const float* W  = kv ? Wv : Wk;
  const float* bb = kv ? bv : bk;
  float* dst      = kv ? v2 : k2;

  __shared__ float ash[16*512];
  __shared__ float part[32][16][8];

  for (int i = t; i < 8192; i += 256) ash[i] = ag[i];
  __syncthreads();
  const int cl = t & 7, ks = t >> 3;
  float s[16];
  #pragma unroll
  for (int a = 0; a < 16; ++a) s[a] = 0.f;
  #pragma unroll
  for (int i = 0; i < 16; ++i) {
    const int cc = ks*16 + i;
    const float wv = W[(size_t)cc*C_ + c0 + cl];
    #pragma unroll
    for (int a = 0; a < 16; ++a) s[a] += ash[a*512 + cc] * wv;
  }
  #pragma unroll
  for (int a = 0; a < 16; ++a) part[ks][a][cl] = s[a];
  __syncthreads();
  if (t < 128) {
    const int a = t >> 3, c = t & 7;
    float v = bb[c0 + c];
    #pragma unroll
    for (int k = 0; k < 32; ++k) v += part[k][a][c];
    dst[a*C_ + c0 + c] = v;
  }
}

// merged: blocks 0..511 -> WqkTr, blocks 512..639 -> WvpTr
// All 256 threads active: 2 threads per output (adjacent lanes), serial chain halved.
__global__ __launch_bounds__(256) void prep_w(
    const float* __restrict__ Wq, const float* __restrict__ bq, const float* __restrict__ k2,
    const float* __restrict__ Wp, const float* __restrict__ v2,
    u16* __restrict__ WqkTr, float* __restrict__ bqk, u16* __restrict__ WvpTr)
{
  const int bx = blockIdx.x;
  const int t = threadIdx.x;
  if (bx < 512) {
    const int ha = t >> 1, half = t & 1;     // 2 adjacent lanes per output
    const int c = bx, h = ha >> 4, a = ha & 15;
    const f32x4* wq4 = (const f32x4*)(Wq + (size_t)c*C_ + h*64) + half*8;
    const f32x4* k24 = (const f32x4*)(k2 + (size_t)a*C_ + h*64) + half*8;
    float s = 0.f;
    #pragma unroll
    for (int d4 = 0; d4 < 8; ++d4) {
      f32x4 wv = wq4[d4], kv = k24[d4];
      s += wv[0]*kv[0] + wv[1]*kv[1] + wv[2]*kv[2] + wv[3]*kv[3];
    }
    s += __shfl_xor(s, 1);
    if (half == 0) {
      const int kt = c >> 5, rg = (c >> 3) & 3, e = c & 7;
      const int ct = ha >> 4, la = ha & 15;
      WqkTr[(((kt*8 + ct)*64) + rg*16 + la)*8 + e] = f2b(s * 0.125f);
    }
    if (c == 0) {
      const f32x4* bq4 = (const f32x4*)(bq + h*64) + half*8;
      float sb = 0.f;
      #pragma unroll
      for (int d4 = 0; d4 < 8; ++d4) {
        f32x4 wv = bq4[d4], kv = k24[d4];
        sb += wv[0]*kv[0] + wv[1]*kv[1] + wv[2]*kv[2] + wv[3]*kv[3];
      }
      sb += __shfl_xor(sb, 1);
      if (half == 0) bqk[ha] = sb * 0.125f;
    }
  } else {
    __shared__ float vsh[64];
    const int ha = bx - 512, h = ha >> 4, a = ha & 15;
    if (t < 64) vsh[t] = v2[a*C_ + h*64 + t];
    __syncthreads();
    const int kt = ha >> 5, rg = (ha >> 3) & 3, e = ha & 7;
    const int half = t & 1;
    #pragma unroll
    for (int it = 0; it < 4; ++it) {
      const int co = it*128 + (t >> 1);
      float s = 0.f;
      #pragma unroll
      for (int d = 0; d < 32; ++d) {
        const int dd = half*32 + d;
        s += vsh[dd] * Wp[(size_t)(h*64 + dd)*C_ + co];
      }
      s += __shfl_xor(s, 1);
      if (half == 0) {
        const int cb = co >> 7, ct = (co >> 4) & 7, la = co & 15;
        WvpTr[((((cb*4 + kt)*8 + ct)*64) + rg*16 + la)*8 + e] = f2b(s);
      }
    }
  }
}

// ---------------- pass A: 64-row tiles, 2048 blocks, 32KB LDS exact, 5 blocks/CU ----------------
__global__ __launch_bounds__(256, 5) void pass_a(
    const float* __restrict__ x, const u16* __restrict__ WqkTr,
    const float* __restrict__ bqk, u16* __restrict__ attn,
    float* __restrict__ gpart)
{
  __shared__ __align__(16) u16 Bs[16384];   // 32 KB exact; ps/pm aliased post-K-loop

  const int t = threadIdx.x;
  const int m0 = blockIdx.x * 64;
  const int w = t >> 6, lane = t & 63;
  const int la = lane & 15, rg = lane >> 4;

  const float* xr = x + (size_t)(m0 + w*16 + la)*C_ + rg*8;

  f32x4 acc[8];
  #pragma unroll
  for (int j = 0; j < 8; ++j) acc[j] = (f32x4){0.f,0.f,0.f,0.f};

  f32x4 pr[2][2];                           // depth-2 kt ring (16 VGPR)
#define LOADKT(slot, kt) \
  pr[slot][0] = *(const f32x4*)(xr + (kt)*32);     \
  pr[slot][1] = *(const f32x4*)(xr + (kt)*32 + 4);

  LOADKT(0, 0); LOADKT(1, 1);

  #pragma unroll
  for (int ph = 0; ph < 4; ++ph) {
    __syncthreads();
    {
      const short8* gs = (const short8*)WqkTr + ph*2048 + t;
      short8* ld = (short8*)Bs + t;
      #pragma unroll
      for (int i = 0; i < 8; ++i) ld[i*256] = gs[i*256];
    }
    __syncthreads();
    #pragma unroll
    for (int k4 = 0; k4 < 4; ++k4) {
      const int kt = ph*4 + k4;
      const int sl = kt & 1;
      short8 b0 = cvt8v(pr[sl][0], pr[sl][1]);
      if (kt < 14) { LOADKT(sl, kt + 2); }
      const u16* fb = Bs + (size_t)k4*4096 + lane*8;
      #pragma unroll
      for (int ct = 0; ct < 8; ++ct) {
        short8 af = *(const short8*)(fb + ct*512);
        acc[ct] = __builtin_amdgcn_mfma_f32_16x16x32_bf16(af, b0, acc[ct], 0, 0, 0);
      }
    }
  }
#undef LOADKT

  // epilogue: softmax over a (in-register) + attn write + gating partials
  float psj[4] = {0.f,0.f,0.f,0.f};
  float pmj[4] = {0.f,0.f,0.f,0.f};
  const int row = m0 + w*16 + la;

  #pragma unroll
  for (int ct = 0; ct < 8; ++ct) {
    const f32x4 bb = *(const f32x4*)(bqk + ct*16 + rg*4);
    float e0 = __expf(acc[ct][0] + bb[0]);
    float e1 = __expf(acc[ct][1] + bb[1]);
    float e2 = __expf(acc[ct][2] + bb[2]);
    float e3 = __expf(acc[ct][3] + bb[3]);
    float s = e0 + e1 + e2 + e3;
    s += __shfl_xor(s, 16); s += __shfl_xor(s, 32);
    float r = __builtin_amdgcn_rcpf(s);
    float p0 = e0*r, p1 = e1*r, p2 = e2*r, p3 = e3*r;
    psj[0] += p0; psj[1] += p1; psj[2] += p2; psj[3] += p3;
    pmj[0] = fmaxf(pmj[0], p0); pmj[1] = fmaxf(pmj[1], p1);
    pmj[2] = fmaxf(pmj[2], p2); pmj[3] = fmaxf(pmj[3], p3);
    short4_t st;
    st[0]=(short)f2b(p0); st[1]=(short)f2b(p1); st[2]=(short)f2b(p2); st[3]=(short)f2b(p3);
    *(short4_t*)(attn + (size_t)row*128 + ct*16 + rg*4) = st;
  }

  __syncthreads();                          // all Bs reads done -> safe to alias ps/pm
  float* psm = (float*)Bs;                  // [0..63]=ps(w,idx), [64..127]=pm(w,idx)
  #pragma unroll
  for (int j = 0; j < 4; ++j) {
    float s = psj[j], m = pmj[j];
    s += __shfl_xor(s, 1); s += __shfl_xor(s, 2); s += __shfl_xor(s, 4); s += __shfl_xor(s, 8);
    m = fmaxf(m, __shfl_xor(m, 1)); m = fmaxf(m, __shfl_xor(m, 2));
    m = fmaxf(m, __shfl_xor(m, 4)); m = fmaxf(m, __shfl_xor(m, 8));
    if (la == 0) { psm[w*16 + rg*4 + j] = s; psm[64 + w*16 + rg*4 + j] = m; }
  }
  __syncthreads();
  if (t < 16) {
    float s = psm[t] + psm[16 + t] + psm[32 + t] + psm[48 + t];
    float m = fmaxf(fmaxf(psm[64 + t], psm[80 + t]), fmaxf(psm[96 + t], psm[112 + t]));
    gpart[(size_t)blockIdx.x*32 + t]      = s;
    gpart[(size_t)blockIdx.x*32 + 16 + t] = m;
  }
}

// ---------------- pass B: 64-row tiles, 2048 blocks, attn read once, 32KB LDS exact ----------------
__global__ __launch_bounds__(256, 5) void pass_b(
    const u16* __restrict__ attn, const u16* __restrict__ WvpTr,
    const float* __restrict__ gpart, const float* __restrict__ ca_w1,
    const float* __restrict__ ca_w2, const float* __restrict__ bp,
    float* __restrict__ out)
{
  __shared__ __align__(16) u16 Bs[16384];   // 32 KB; gsh aliased pre-staging
  const int bx = blockIdx.x;
  const int mb = (bx & 7)*256 + (bx >> 3);  // XCD swizzle over 2048
  const int b = mb >> 6;
  const int t = threadIdx.x;
  const int w = t >> 6, lane = t & 63;
  const int la = lane & 15, rg = lane >> 4;
  const int row = mb*64 + w*16 + la;

  // attn fragments once
  const u16* br = attn + (size_t)row*128 + rg*8;
  short8 bf[4];
  #pragma unroll
  for (int kt = 0; kt < 4; ++kt) bf[kt] = *(const short8*)(br + kt*32);

  // gate MLP from per-block partials (t<16), gsh aliased onto Bs
  float* ga = (float*)Bs;
  if (t < 16) {
    float s = 0.f, m = 0.f;
    #pragma unroll 4
    for (int blk = 0; blk < 64; ++blk) {
      const float* gp = gpart + (size_t)(b*64 + blk)*32;
      s += gp[t]; m = fmaxf(m, gp[16 + t]);
    }
    float c1 = s * (1.0f/32768.0f) * ca_w1[t];
    float c2 = m * ca_w1[t];
    c1 += __shfl_xor(c1, 1); c1 += __shfl_xor(c1, 2); c1 += __shfl_xor(c1, 4); c1 += __shfl_xor(c1, 8);
    c2 += __shfl_xor(c2, 1); c2 += __shfl_xor(c2, 2); c2 += __shfl_xor(c2, 4); c2 += __shfl_xor(c2, 8);
    float g1 = fmaxf(c1, 0.f) + fmaxf(c2, 0.f);
    ga[t] = 1.f / (1.f + __expf(-g1 * ca_w2[t]));
  }
  __syncthreads();

  // gate folded into P-fragments once: k&15 = (rg&1)*8 + e
  float ge[8];
  #pragma unroll
  for (int e = 0; e < 8; ++e) ge[e] = ga[(rg & 1)*8 + e];
  #pragma unroll
  for (int kt = 0; kt < 4; ++kt) {
    short8 v0 = bf[kt];
    #pragma unroll
    for (int e = 0; e < 8; ++e) v0[e] = (short)f2b(b2f((u16)v0[e]) * ge[e]);
    bf[kt] = v0;
  }

  #pragma unroll 1
  for (int cb = 0; cb < 4; ++cb) {
    __syncthreads();                        // gsh consumed / prior cb reads done
    {
      const short8* gs = (const short8*)WvpTr + cb*2048 + t;
      short8* ld = (short8*)Bs + t;
      #pragma unroll
      for (int i = 0; i < 8; ++i) ld[i*256] = gs[i*256];
    }
    __syncthreads();

    f32x4 acc[8];
    #pragma unroll
    for (int j = 0; j < 8; ++j) acc[j] = (f32x4){0.f,0.f,0.f,0.f};

    #pragma unroll
    for (int kt = 0; kt < 4; ++kt) {
      const u16* fb = Bs + (size_t)kt*4096 + lane*8;
      #pragma unroll
      for (int ct = 0; ct < 8; ++ct) {
        short8 af = *(const short8*)(fb + ct*512);
        acc[ct] = __builtin_amdgcn_mfma_f32_16x16x32_bf16(af, bf[kt], acc[ct], 0, 0, 0);
      }
    }

    #pragma unroll
    for (int ct = 0; ct < 8; ++ct) {
      const int col = cb*128 + ct*16 + rg*4;
      const f32x4 bb = *(const f32x4*)(bp + col);
      f32x4 o;
      o[0] = acc[ct][0] + bb[0];
      o[1] = acc[ct][1] + bb[1];
      o[2] = acc[ct][2] + bb[2];
      o[3] = acc[ct][3] + bb[3];
      *(f32x4*)(out + (size_t)row*C_ + col) = o;
    }
  }
}

// ---------------- launch ----------------
extern "C" void kernel_launch(void* const* d_in, const int* in_sizes, int n_in,
                              void* d_out, int out_size, void* d_ws, size_t ws_size,
                              hipStream_t stream)
{
  const float* x       = (const float*)d_in[0];
  const float* Wq      = (const float*)d_in[1];
  const float* bq      = (const float*)d_in[2];
  const float* Wk      = (const float*)d_in[3];
  const float* bk      = (const float*)d_in[4];
  const float* Wv      = (const float*)d_in[5];
  const float* bv      = (const float*)d_in[6];
  const float* Wp      = (const float*)d_in[7];
  const float* bp      = (const float*)d_in[8];
  const float* agent_k = (const float*)d_in[9];
  const float* agent_v = (const float*)d_in[10];
  const float* ca_w1   = (const float*)d_in[11];
  const float* ca_w2   = (const float*)d_in[12];
  float* out = (float*)d_out;

  char* ws = (char*)d_ws;
  u16*   attn   = (u16*)(ws);                          // 33,554,432 B
  float* k2     = (float*)(ws + 33554432);             // 32768
  float* v2     = (float*)(ws + 33587200);             // 32768
  u16*   WqkTr  = (u16*)(ws + 33619968);               // 131072
  float* bqk    = (float*)(ws + 33751040);             // 2048
  u16*   WvpTr  = (u16*)(ws + 33753088);               // 131072
  float* gpart  = (float*)(ws + 33884160);             // 2048*32*4 = 262144

  prep_kv<<<128, 256, 0, stream>>>(agent_k, Wk, bk, agent_v, Wv, bv, k2, v2);
  prep_w<<<640, 256, 0, stream>>>(Wq, bq, k2, Wp, v2, WqkTr, bqk, WvpTr);
  pass_a<<<2048, 256, 0, stream>>>(x, WqkTr, bqk, attn, gpart);
  pass_b<<<2048, 256, 0, stream>>>(attn, WvpTr, gpart, ca_w1, ca_w2, bp, out);
}